// Round 1
// baseline (16925.308 us; speedup 1.0000x reference)
//
#include <hip/hip_runtime.h>
#include <hip/hip_bf16.h>

// ---- problem constants ----
constexpr int kB   = 32;
constexpr int kL   = 12;
constexpr int kN   = 325;
constexpr int kNP  = 328;          // padded node count (mult of 8 -> 16B-aligned float4 rows)
constexpr int kPc  = kB * kNP;     // 10496 column stride for channel-major buffers
constexpr int kHID = 64;
constexpr int kDIN = 198;          // 3 * 66
constexpr int kND  = 40;
constexpr float cAW = 0.05f, cBW = 0.95f, cGW = 0.95f, cTA = 3.0f;

__device__ __forceinline__ float sigm_f(float x) { return 1.f / (1.f + __expf(-x)); }
__device__ __forceinline__ float tanh_f(float x) { return 1.f - 2.f / (1.f + __expf(2.f * x)); }

// ---------------------------------------------------------------------------
// init: H=0, prev=0, transpose emb -> [40][325]
__global__ void k_init(const float* emb1, const float* emb2,
                       float* Hm, float* prev, float* e1T, float* e2T) {
    int tid = blockIdx.x * 256 + threadIdx.x;
    if (tid < 64 * kPc) { Hm[tid] = 0.f; return; }
    tid -= 64 * kPc;
    if (tid < kPc) { prev[tid] = 0.f; return; }
    tid -= kPc;
    if (tid < 40 * kN) { int d = tid / kN, n = tid - d * kN; e1T[tid] = emb1[n * kND + d]; return; }
    tid -= 40 * kN;
    if (tid < 40 * kN) { int d = tid / kN, n = tid - d * kN; e2T[tid] = emb2[n * kND + d]; }
}

// ---------------------------------------------------------------------------
// build x|H into rows 0..65 of the 4 diffusion buffers (channel-major)
__global__ void k_build(const float* hist, const float* fut, const float* Hm,
                        const float* prev, int t, int dec,
                        float* d0, float* d1, float* d2, float* d3) {
    int tid = blockIdx.x * 256 + threadIdx.x;
    if (tid >= 66 * kPc) return;
    int c = tid / kPc, p = tid - c * kPc;
    int b = p / kNP, n = p - b * kNP;
    if (n >= kN) return;
    float v;
    if (c >= 2)       v = Hm[(c - 2) * kPc + p];
    else if (!dec)    v = hist[((b * kL + t) * kN + n) * 2 + c];
    else if (c == 0)  v = prev[p];
    else              v = fut[((b * kL + t) * kN + n) * 2 + 1];
    d0[c * kPc + p] = v; d1[c * kPc + p] = v; d2[c * kPc + p] = v; d3[c * kPc + p] = v;
}

// ---------------------------------------------------------------------------
// diffusion hop: out[c,col] = gamma * sum_v M[v,w]*h[c, b, v]  + AW * x[c,col]
struct Chain {
    const float* M; int mstride; const float* h; const float* x; float* out; float gamma;
};

__global__ __launch_bounds__(64) void k_hop(Chain ca, Chain cb) {
    const int zb = blockIdx.z;
    const Chain ch = (zb >= 32) ? cb : ca;
    const int b = zb & 31;
    const int w = blockIdx.x * 64 + threadIdx.x;
    if (w >= kN) return;
    const int c0r = blockIdx.y * 11;
    const float* Mp = ch.M + (size_t)b * ch.mstride + w;
    const float* hb = ch.h + b * kNP;
    float acc[11];
#pragma unroll
    for (int i = 0; i < 11; ++i) acc[i] = 0.f;
    for (int vc = 0; vc < 320; vc += 8) {
        float m0 = Mp[(vc + 0) * kN], m1 = Mp[(vc + 1) * kN];
        float m2 = Mp[(vc + 2) * kN], m3 = Mp[(vc + 3) * kN];
        float m4 = Mp[(vc + 4) * kN], m5 = Mp[(vc + 5) * kN];
        float m6 = Mp[(vc + 6) * kN], m7 = Mp[(vc + 7) * kN];
#pragma unroll
        for (int i = 0; i < 11; ++i) {
            const float* hr = hb + (c0r + i) * kPc + vc;
            float4 A = *(const float4*)hr;
            float4 C = *(const float4*)(hr + 4);
            float s = acc[i];
            s = fmaf(m0, A.x, s); s = fmaf(m1, A.y, s);
            s = fmaf(m2, A.z, s); s = fmaf(m3, A.w, s);
            s = fmaf(m4, C.x, s); s = fmaf(m5, C.y, s);
            s = fmaf(m6, C.z, s); s = fmaf(m7, C.w, s);
            acc[i] = s;
        }
    }
    for (int v = 320; v < kN; ++v) {
        float m = Mp[v * kN];
#pragma unroll
        for (int i = 0; i < 11; ++i) acc[i] = fmaf(m, hb[(c0r + i) * kPc + v], acc[i]);
    }
    const int col = b * kNP + w;
#pragma unroll
    for (int i = 0; i < 11; ++i)
        ch.out[(c0r + i) * kPc + col] = ch.gamma * acc[i] + cAW * ch.x[(c0r + i) * kPc + col];
}

// ---------------------------------------------------------------------------
// hyper fc1 (198->16, sigmoid) for the 4 mlp instances
__global__ __launch_bounds__(64) void k_mlp1(const float* src0, const float* src1,
                                             const float* w1, const float* b1,
                                             float* s1, int hy0) {
    int p = blockIdx.x * 64 + threadIdx.x;
    int m = blockIdx.y;
    int ig = hy0 + m;
    const float* src = (m & 1) ? src1 : src0;
    const float* wp = w1 + ig * (kDIN * 16);
    float acc[16];
#pragma unroll
    for (int o = 0; o < 16; ++o) acc[o] = 0.f;
    for (int k = 0; k < kDIN; ++k) {
        float u = src[k * kPc + p];
#pragma unroll
        for (int o = 0; o < 16; ++o) acc[o] = fmaf(u, wp[k * 16 + o], acc[o]);
    }
#pragma unroll
    for (int o = 0; o < 16; ++o)
        s1[(m * 16 + o) * kPc + p] = sigm_f(acc[o] + b1[ig * 16 + o]);
}

// fc2 (16->2, sigmoid), fc3 (2->40), combine f1/f2, nv = tanh(TA*emb*f)
__global__ __launch_bounds__(64) void k_mlp2(const float* s1, const float* w2, const float* b2,
                                             const float* w3, const float* b3,
                                             const float* e1T, const float* e2T,
                                             float* nv1, float* nv2, int hy0) {
    int p = blockIdx.x * 64 + threadIdx.x;
    int b = p / kNP, n = p - b * kNP;
    if (n >= kN) return;
    float s2[4][2];
    for (int m = 0; m < 4; ++m) {
        int ig = hy0 + m;
        float sv[16];
#pragma unroll
        for (int o = 0; o < 16; ++o) sv[o] = s1[(m * 16 + o) * kPc + p];
#pragma unroll
        for (int j = 0; j < 2; ++j) {
            float t = b2[ig * 2 + j];
#pragma unroll
            for (int o = 0; o < 16; ++o) t = fmaf(sv[o], w2[ig * 32 + o * 2 + j], t);
            s2[m][j] = sigm_f(t);
        }
    }
    int i0 = hy0;
    for (int d = 0; d < kND; ++d) {
        float f1 = b3[(i0 + 0) * kND + d] + b3[(i0 + 1) * kND + d]
                 + s2[0][0] * w3[(i0 + 0) * 80 + d] + s2[0][1] * w3[(i0 + 0) * 80 + 40 + d]
                 + s2[1][0] * w3[(i0 + 1) * 80 + d] + s2[1][1] * w3[(i0 + 1) * 80 + 40 + d];
        float f2 = b3[(i0 + 2) * kND + d] + b3[(i0 + 3) * kND + d]
                 + s2[2][0] * w3[(i0 + 2) * 80 + d] + s2[2][1] * w3[(i0 + 2) * 80 + 40 + d]
                 + s2[3][0] * w3[(i0 + 3) * 80 + d] + s2[3][1] * w3[(i0 + 3) * 80 + 40 + d];
        nv1[d * kPc + p] = tanh_f(cTA * e1T[d * kN + n] * f1);
        nv2[d * kPc + p] = tanh_f(cTA * e2T[d * kN + n] * f2);
    }
}

// ---------------------------------------------------------------------------
// a[b,i,j] = sum_d nv1[d,b,i] * nv2[d,b,j]
__global__ __launch_bounds__(64) void k_agemm(const float* nv1, const float* nv2, float* a) {
    int j = blockIdx.x * 64 + threadIdx.x;
    int i0 = blockIdx.y * 4;
    int b = blockIdx.z;
    const float* n2 = nv2 + b * kNP + j;
    const float* n1 = nv1 + b * kNP + i0;
    float acc[4] = {0.f, 0.f, 0.f, 0.f};
    for (int d = 0; d < kND; ++d) {
        float vj = n2[d * kPc];
#pragma unroll
        for (int q = 0; q < 4; ++q) acc[q] = fmaf(n1[d * kPc + q], vj, acc[q]);
    }
    if (j < kN) {
#pragma unroll
        for (int q = 0; q < 4; ++q)
            if (i0 + q < kN) a[((size_t)(b * kN + i0 + q)) * kN + j] = acc[q];
    }
}

// adjv = relu(tanh(TA*(a - a^T)))
__global__ __launch_bounds__(64) void k_adjsym(const float* a, float* adjv) {
    int j = blockIdx.x * 64 + threadIdx.x;
    if (j >= kN) return;
    int i = blockIdx.y, b = blockIdx.z;
    float aij = a[((size_t)(b * kN + i)) * kN + j];
    float aji = a[((size_t)(b * kN + j)) * kN + i];
    float t = tanh_f(cTA * (aij - aji));
    adjv[((size_t)(b * kN + i)) * kN + j] = fmaxf(t, 0.f);
}

// irs0 = 1/(1+rowsum), irs1 = 1/(1+colsum)
__global__ __launch_bounds__(64) void k_rowsum(const float* adjv, float* irs0, float* irs1) {
    int i = blockIdx.x * 64 + threadIdx.x;
    if (i >= kN) return;
    int b = blockIdx.y;
    const float* base = adjv + (size_t)b * kN * kN;
    float rs = 1.f, cs = 1.f;
#pragma unroll 4
    for (int j = 0; j < kN; ++j) {
        cs += base[j * kN + i];
        rs += base[i * kN + j];
    }
    irs0[b * kN + i] = 1.f / rs;
    irs1[b * kN + i] = 1.f / cs;
}

// E0[v,w] = BW*(adjv[v,w]+I)/rs0[v] + GW*adj0[v,w] ; E1 uses adjv^T and colsum norm
__global__ __launch_bounds__(64) void k_buildE(const float* adjv, const float* adj0, const float* adj1,
                                               const float* irs0, const float* irs1,
                                               float* E0, float* E1) {
    int w = blockIdx.x * 64 + threadIdx.x;
    if (w >= kN) return;
    int v = blockIdx.y, b = blockIdx.z;
    const float* av = adjv + (size_t)b * kN * kN;
    float i0 = irs0[b * kN + v], i1 = irs1[b * kN + v];
    float e0 = cBW * av[v * kN + w] * i0 + cGW * adj0[v * kN + w];
    float e1 = cBW * av[w * kN + v] * i1 + cGW * adj1[v * kN + w];
    if (v == w) { e0 += cBW * i0; e1 += cBW * i1; }
    size_t o = (size_t)b * kN * kN + v * kN + w;
    E0[o] = e0; E1[o] = e1;
}

// ---------------------------------------------------------------------------
// z,r gates + temp = [x, r*H] written into ho_c buffers
__global__ __launch_bounds__(64) void k_gates(const float* hz0, const float* hz1,
                                              const float* rnw, const float* rnb, int rb,
                                              const float* Hm, float* z,
                                              float* tc0, float* tc1) {
    int p = blockIdx.x * 64 + threadIdx.x;
    int h0 = blockIdx.y * 8;
    const float* wz0 = rnw + (rb + 0) * (kDIN * kHID) + h0;
    const float* wz1 = rnw + (rb + 1) * (kDIN * kHID) + h0;
    const float* wr0 = rnw + (rb + 2) * (kDIN * kHID) + h0;
    const float* wr1 = rnw + (rb + 3) * (kDIN * kHID) + h0;
    float az[8], ar[8];
#pragma unroll
    for (int i = 0; i < 8; ++i) { az[i] = 0.f; ar[i] = 0.f; }
    for (int k = 0; k < kDIN; ++k) {
        float u0 = hz0[k * kPc + p], u1 = hz1[k * kPc + p];
#pragma unroll
        for (int i = 0; i < 8; ++i) {
            az[i] = fmaf(u0, wz0[k * kHID + i], az[i]);
            az[i] = fmaf(u1, wz1[k * kHID + i], az[i]);
            ar[i] = fmaf(u0, wr0[k * kHID + i], ar[i]);
            ar[i] = fmaf(u1, wr1[k * kHID + i], ar[i]);
        }
    }
    int b = p / kNP, n = p - b * kNP;
    bool ok = (n < kN);
#pragma unroll
    for (int i = 0; i < 8; ++i) {
        float zz = sigm_f(az[i] + rnb[(rb + 0) * kHID + h0 + i] + rnb[(rb + 1) * kHID + h0 + i]);
        float rr = sigm_f(ar[i] + rnb[(rb + 2) * kHID + h0 + i] + rnb[(rb + 3) * kHID + h0 + i]);
        float tv = rr * Hm[(h0 + i) * kPc + p];
        if (ok) {
            z[(h0 + i) * kPc + p] = zz;
            tc0[(2 + h0 + i) * kPc + p] = tv;
            tc1[(2 + h0 + i) * kPc + p] = tv;
        }
    }
    if (blockIdx.y == 0 && ok) {
#pragma unroll
        for (int c = 0; c < 2; ++c) {
            float xv = hz0[c * kPc + p];
            tc0[c * kPc + p] = xv; tc1[c * kPc + p] = xv;
        }
    }
}

// Cn + GRU update: H = z*H + (1-z)*tanh(...)
__global__ __launch_bounds__(64) void k_final(const float* hc0, const float* hc1,
                                              const float* rnw, const float* rnb, int rb,
                                              const float* z, float* Hm) {
    int p = blockIdx.x * 64 + threadIdx.x;
    int h0 = blockIdx.y * 8;
    const float* wc0 = rnw + (rb + 4) * (kDIN * kHID) + h0;
    const float* wc1 = rnw + (rb + 5) * (kDIN * kHID) + h0;
    float ac[8];
#pragma unroll
    for (int i = 0; i < 8; ++i) ac[i] = 0.f;
    for (int k = 0; k < kDIN; ++k) {
        float u0 = hc0[k * kPc + p], u1 = hc1[k * kPc + p];
#pragma unroll
        for (int i = 0; i < 8; ++i) {
            ac[i] = fmaf(u0, wc0[k * kHID + i], ac[i]);
            ac[i] = fmaf(u1, wc1[k * kHID + i], ac[i]);
        }
    }
    int b = p / kNP, n = p - b * kNP;
    if (n >= kN) return;
#pragma unroll
    for (int i = 0; i < 8; ++i) {
        float cn = tanh_f(ac[i] + rnb[(rb + 4) * kHID + h0 + i] + rnb[(rb + 5) * kHID + h0 + i]);
        float zz = z[(h0 + i) * kPc + p];
        float hv = Hm[(h0 + i) * kPc + p];
        Hm[(h0 + i) * kPc + p] = zz * hv + (1.f - zz) * cn;
    }
}

// decoder readout: out = H @ fc_w + fc_b ; prev = out
__global__ __launch_bounds__(64) void k_out(const float* Hm, const float* fw, const float* fb,
                                            float* out, float* prev, int t) {
    int p = blockIdx.x * 64 + threadIdx.x;
    int b = p / kNP, n = p - b * kNP;
    if (n >= kN) return;
    float acc = fb[0];
#pragma unroll
    for (int h = 0; h < kHID; ++h) acc = fmaf(Hm[h * kPc + p], fw[h], acc);
    out[(b * 12 + t) * kN + n] = acc;
    prev[p] = acc;
}

// ---------------------------------------------------------------------------
extern "C" void kernel_launch(void* const* d_in, const int* in_sizes, int n_in,
                              void* d_out, int out_size, void* d_ws, size_t ws_size,
                              hipStream_t stream) {
    const float* hist = (const float*)d_in[0];
    const float* fut  = (const float*)d_in[1];
    const float* adj0 = (const float*)d_in[2];
    const float* adj1 = (const float*)d_in[3];
    const float* emb1 = (const float*)d_in[4];
    const float* emb2 = (const float*)d_in[5];
    const float* hw1  = (const float*)d_in[6];
    const float* hb1  = (const float*)d_in[7];
    const float* hw2  = (const float*)d_in[8];
    const float* hb2  = (const float*)d_in[9];
    const float* hw3  = (const float*)d_in[10];
    const float* hb3  = (const float*)d_in[11];
    const float* rnw  = (const float*)d_in[12];
    const float* rnb  = (const float*)d_in[13];
    const float* fcw  = (const float*)d_in[14];
    const float* fcb  = (const float*)d_in[15];
    float* out = (float*)d_out;
    float* ws  = (float*)d_ws;

    // workspace layout (floats)
    size_t off = 0;
    float* Hm   = ws + off; off += 64 * kPc;
    float* hoh0 = ws + off; off += kDIN * kPc;   // hyper chain A0 (reused as ho_c0)
    float* hoh1 = ws + off; off += kDIN * kPc;   // hyper chain A1 (reused as ho_c1)
    float* hoz0 = ws + off; off += kDIN * kPc;   // rnn chain adp/adj0
    float* hoz1 = ws + off; off += kDIN * kPc;   // rnn chain adpT/adj1
    float* nv1  = ws + off; off += kND * kPc;
    float* nv2  = ws + off; off += kND * kPc;
    float* s1   = ws + off; off += 64 * kPc;
    float* zbuf = ws + off; off += 64 * kPc;
    float* prev = ws + off; off += kPc;
    float* abuf = ws + off; off += (size_t)kB * kN * kN;   // also E0 (a dead after adjsym)
    float* adjv = ws + off; off += (size_t)kB * kN * kN;
    float* E1   = ws + off; off += (size_t)kB * kN * kN;
    float* irs0 = ws + off; off += kB * kN;
    float* irs1 = ws + off; off += kB * kN;
    float* e1T  = ws + off; off += kND * kN;
    float* e2T  = ws + off; off += kND * kN;
    float* E0   = abuf;
    float* hoc0 = hoh0;
    float* hoc1 = hoh1;

    const int NN2 = kN * kN;

    {
        int tot = 64 * kPc + kPc + 2 * kND * kN;
        k_init<<<dim3((tot + 255) / 256), dim3(256), 0, stream>>>(emb1, emb2, Hm, prev, e1T, e2T);
    }

    for (int step = 0; step < 24; ++step) {
        int dec = step >= 12;
        int t = dec ? step - 12 : step;
        int hy0 = dec ? 4 : 0;
        int rb = dec ? 6 : 0;

        k_build<<<dim3((66 * kPc) / 256), dim3(256), 0, stream>>>(
            hist, fut, Hm, prev, t, dec, hoh0, hoh1, hoz0, hoz1);

        // hyper diffusion (static adjacencies)
        {
            Chain ca{adj0, 0, hoh0, hoh0, hoh0 + 66 * kPc, cGW};
            Chain cb{adj1, 0, hoh1, hoh1, hoh1 + 66 * kPc, cGW};
            k_hop<<<dim3(6, 6, 64), dim3(64), 0, stream>>>(ca, cb);
        }
        {
            Chain ca{adj0, 0, hoh0 + 66 * kPc, hoh0, hoh0 + 132 * kPc, cGW};
            Chain cb{adj1, 0, hoh1 + 66 * kPc, hoh1, hoh1 + 132 * kPc, cGW};
            k_hop<<<dim3(6, 6, 64), dim3(64), 0, stream>>>(ca, cb);
        }

        k_mlp1<<<dim3(kPc / 64, 4), dim3(64), 0, stream>>>(hoh0, hoh1, hw1, hb1, s1, hy0);
        k_mlp2<<<dim3(kPc / 64), dim3(64), 0, stream>>>(s1, hw2, hb2, hw3, hb3, e1T, e2T, nv1, nv2, hy0);

        k_agemm<<<dim3(6, 82, kB), dim3(64), 0, stream>>>(nv1, nv2, abuf);
        k_adjsym<<<dim3(6, kN, kB), dim3(64), 0, stream>>>(abuf, adjv);
        k_rowsum<<<dim3(6, kB), dim3(64), 0, stream>>>(adjv, irs0, irs1);
        k_buildE<<<dim3(6, kN, kB), dim3(64), 0, stream>>>(adjv, adj0, adj1, irs0, irs1, E0, E1);

        // rnn diffusion on hi
        {
            Chain ca{E0, NN2, hoz0, hoz0, hoz0 + 66 * kPc, 1.f};
            Chain cb{E1, NN2, hoz1, hoz1, hoz1 + 66 * kPc, 1.f};
            k_hop<<<dim3(6, 6, 64), dim3(64), 0, stream>>>(ca, cb);
        }
        {
            Chain ca{E0, NN2, hoz0 + 66 * kPc, hoz0, hoz0 + 132 * kPc, 1.f};
            Chain cb{E1, NN2, hoz1 + 66 * kPc, hoz1, hoz1 + 132 * kPc, 1.f};
            k_hop<<<dim3(6, 6, 64), dim3(64), 0, stream>>>(ca, cb);
        }

        k_gates<<<dim3(kPc / 64, 8), dim3(64), 0, stream>>>(hoz0, hoz1, rnw, rnb, rb, Hm, zbuf, hoc0, hoc1);

        // rnn diffusion on temp
        {
            Chain ca{E0, NN2, hoc0, hoc0, hoc0 + 66 * kPc, 1.f};
            Chain cb{E1, NN2, hoc1, hoc1, hoc1 + 66 * kPc, 1.f};
            k_hop<<<dim3(6, 6, 64), dim3(64), 0, stream>>>(ca, cb);
        }
        {
            Chain ca{E0, NN2, hoc0 + 66 * kPc, hoc0, hoc0 + 132 * kPc, 1.f};
            Chain cb{E1, NN2, hoc1 + 66 * kPc, hoc1, hoc1 + 132 * kPc, 1.f};
            k_hop<<<dim3(6, 6, 64), dim3(64), 0, stream>>>(ca, cb);
        }

        k_final<<<dim3(kPc / 64, 8), dim3(64), 0, stream>>>(hoc0, hoc1, rnw, rnb, rb, zbuf, Hm);

        if (dec)
            k_out<<<dim3(kPc / 64), dim3(64), 0, stream>>>(Hm, fcw, fcb, out, prev, t);
    }
    (void)in_sizes; (void)n_in; (void)out_size; (void)ws_size;
}

// Round 2
// 12618.182 us; speedup vs baseline: 1.3413x; 1.3413x over previous
//
#include <hip/hip_runtime.h>
#include <hip/hip_bf16.h>

// ---- problem constants ----
constexpr int kB   = 32;
constexpr int kL   = 12;
constexpr int kN   = 325;
constexpr int kNP  = 328;          // padded node count (16B-aligned rows)
constexpr int kPc  = kB * kNP;     // 10496 column stride, channel-major
constexpr int kHID = 64;
constexpr int kDIN = 198;          // 3 * 66
constexpr int kND  = 40;
constexpr float cAW = 0.05f, cBW = 0.95f, cGW = 0.95f, cTA = 3.0f;
constexpr int kKS = 160;           // split-K boundary (16B-aligned h loads both halves)

__device__ __forceinline__ float sigm_f(float x) { return 1.f / (1.f + __expf(-x)); }
__device__ __forceinline__ float tanh_f(float x) { return 1.f - 2.f / (1.f + __expf(2.f * x)); }

// ---------------------------------------------------------------------------
__global__ void k_init(const float* __restrict__ emb1, const float* __restrict__ emb2,
                       float* __restrict__ Hm, float* __restrict__ prev,
                       float* __restrict__ e1T, float* __restrict__ e2T) {
    int tid = blockIdx.x * 256 + threadIdx.x;
    if (tid < 64 * kPc) { Hm[tid] = 0.f; return; }
    tid -= 64 * kPc;
    if (tid < kPc) { prev[tid] = 0.f; return; }
    tid -= kPc;
    if (tid < 40 * kN) { int d = tid / kN, n = tid - d * kN; e1T[tid] = emb1[n * kND + d]; return; }
    tid -= 40 * kN;
    if (tid < 40 * kN) { int d = tid / kN, n = tid - d * kN; e2T[tid] = emb2[n * kND + d]; }
}

// ---------------------------------------------------------------------------
// build x|H into rows 0..65 of the 4 diffusion buffers AND prefill the hop
// output slots (rows 66..131, 132..197) with AW*x so hops can atomicAdd.
__global__ void k_build(const float* __restrict__ hist, const float* __restrict__ fut,
                        const float* __restrict__ Hm, const float* __restrict__ prev,
                        int t, int dec,
                        float* __restrict__ d0, float* __restrict__ d1,
                        float* __restrict__ d2, float* __restrict__ d3) {
    int tid = blockIdx.x * 256 + threadIdx.x;
    if (tid >= 66 * kPc) return;
    int c = tid / kPc, p = tid - c * kPc;
    int b = p / kNP, n = p - b * kNP;
    if (n >= kN) return;
    float v;
    if (c >= 2)       v = Hm[(c - 2) * kPc + p];
    else if (!dec)    v = hist[((b * kL + t) * kN + n) * 2 + c];
    else if (c == 0)  v = prev[p];
    else              v = fut[((b * kL + t) * kN + n) * 2 + 1];
    float av = cAW * v;
    d0[c * kPc + p] = v; d0[(66 + c) * kPc + p] = av; d0[(132 + c) * kPc + p] = av;
    d1[c * kPc + p] = v; d1[(66 + c) * kPc + p] = av; d1[(132 + c) * kPc + p] = av;
    d2[c * kPc + p] = v; d2[(66 + c) * kPc + p] = av; d2[(132 + c) * kPc + p] = av;
    d3[c * kPc + p] = v; d3[(66 + c) * kPc + p] = av; d3[(132 + c) * kPc + p] = av;
}

// ---------------------------------------------------------------------------
// diffusion hop (split-K x2): out[c,col] += gamma * sum_{v in half} M[v,w]*h[c,b,v]
// grid (6 wblk, 6 cblk, 128 = half*64 + chain*32 + b), block 64
__global__ __launch_bounds__(64) void k_hop(const float* __restrict__ Ma, const float* __restrict__ Mb,
                                            int mstride,
                                            const float* __restrict__ ha, const float* __restrict__ hbuf,
                                            float* __restrict__ oa, float* __restrict__ ob,
                                            float gamma) {
    const int z = blockIdx.z;
    const int half = z >> 6;
    const int zb = z & 63;
    const int sel = zb >> 5;
    const int b = zb & 31;
    const int w = blockIdx.x * 64 + threadIdx.x;
    if (w >= kN) return;
    const int c0r = blockIdx.y * 11;
    const float* M = sel ? Mb : Ma;
    const float* h = sel ? hbuf : ha;
    float* out = sel ? ob : oa;
    const int vlo = half ? kKS : 0;
    const int vhi = half ? kN : kKS;
    const float* Mp = M + (size_t)b * mstride + w;
    const float* hb = h + b * kNP;
    float acc[11];
#pragma unroll
    for (int i = 0; i < 11; ++i) acc[i] = 0.f;
    int vc = vlo;
    for (; vc + 8 <= vhi; vc += 8) {
        float m0 = Mp[(vc + 0) * kN], m1 = Mp[(vc + 1) * kN];
        float m2 = Mp[(vc + 2) * kN], m3 = Mp[(vc + 3) * kN];
        float m4 = Mp[(vc + 4) * kN], m5 = Mp[(vc + 5) * kN];
        float m6 = Mp[(vc + 6) * kN], m7 = Mp[(vc + 7) * kN];
#pragma unroll
        for (int i = 0; i < 11; ++i) {
            const float* hr = hb + (c0r + i) * kPc + vc;
            float4 A = *(const float4*)hr;
            float4 C = *(const float4*)(hr + 4);
            float s = acc[i];
            s = fmaf(m0, A.x, s); s = fmaf(m1, A.y, s);
            s = fmaf(m2, A.z, s); s = fmaf(m3, A.w, s);
            s = fmaf(m4, C.x, s); s = fmaf(m5, C.y, s);
            s = fmaf(m6, C.z, s); s = fmaf(m7, C.w, s);
            acc[i] = s;
        }
    }
    for (; vc < vhi; ++vc) {
        float m = Mp[vc * kN];
#pragma unroll
        for (int i = 0; i < 11; ++i) acc[i] = fmaf(m, hb[(c0r + i) * kPc + vc], acc[i]);
    }
    const int col = b * kNP + w;
#pragma unroll
    for (int i = 0; i < 11; ++i)
        atomicAdd(&out[(c0r + i) * kPc + col], gamma * acc[i]);
}

// ---------------------------------------------------------------------------
// hyper fc1 (198->16, sigmoid) for the 4 mlp instances
__global__ __launch_bounds__(64) void k_mlp1(const float* __restrict__ src0, const float* __restrict__ src1,
                                             const float* __restrict__ w1, const float* __restrict__ b1,
                                             float* __restrict__ s1, int hy0) {
    int p = blockIdx.x * 64 + threadIdx.x;
    int m = blockIdx.y;
    int ig = hy0 + m;
    const float* src = (m & 1) ? src1 : src0;
    const float* wp = w1 + ig * (kDIN * 16);
    float acc[16];
#pragma unroll
    for (int o = 0; o < 16; ++o) acc[o] = 0.f;
#pragma unroll 2
    for (int k = 0; k < kDIN; ++k) {
        float u = src[k * kPc + p];
#pragma unroll
        for (int o = 0; o < 16; ++o) acc[o] = fmaf(u, wp[k * 16 + o], acc[o]);
    }
#pragma unroll
    for (int o = 0; o < 16; ++o)
        s1[(m * 16 + o) * kPc + p] = sigm_f(acc[o] + b1[ig * 16 + o]);
}

// fc2 (16->2, sigmoid), fc3 (2->40), combine f1/f2, nv = tanh(TA*emb*f)
__global__ __launch_bounds__(64) void k_mlp2(const float* __restrict__ s1,
                                             const float* __restrict__ w2, const float* __restrict__ b2,
                                             const float* __restrict__ w3, const float* __restrict__ b3,
                                             const float* __restrict__ e1T, const float* __restrict__ e2T,
                                             float* __restrict__ nv1, float* __restrict__ nv2, int hy0) {
    int p = blockIdx.x * 64 + threadIdx.x;
    int b = p / kNP, n = p - b * kNP;
    if (n >= kN) return;
    float s2[4][2];
    for (int m = 0; m < 4; ++m) {
        int ig = hy0 + m;
        float sv[16];
#pragma unroll
        for (int o = 0; o < 16; ++o) sv[o] = s1[(m * 16 + o) * kPc + p];
#pragma unroll
        for (int j = 0; j < 2; ++j) {
            float t = b2[ig * 2 + j];
#pragma unroll
            for (int o = 0; o < 16; ++o) t = fmaf(sv[o], w2[ig * 32 + o * 2 + j], t);
            s2[m][j] = sigm_f(t);
        }
    }
    int i0 = hy0;
#pragma unroll 4
    for (int d = 0; d < kND; ++d) {
        float f1 = b3[(i0 + 0) * kND + d] + b3[(i0 + 1) * kND + d]
                 + s2[0][0] * w3[(i0 + 0) * 80 + d] + s2[0][1] * w3[(i0 + 0) * 80 + 40 + d]
                 + s2[1][0] * w3[(i0 + 1) * 80 + d] + s2[1][1] * w3[(i0 + 1) * 80 + 40 + d];
        float f2 = b3[(i0 + 2) * kND + d] + b3[(i0 + 3) * kND + d]
                 + s2[2][0] * w3[(i0 + 2) * 80 + d] + s2[2][1] * w3[(i0 + 2) * 80 + 40 + d]
                 + s2[3][0] * w3[(i0 + 3) * 80 + d] + s2[3][1] * w3[(i0 + 3) * 80 + 40 + d];
        nv1[d * kPc + p] = tanh_f(cTA * e1T[d * kN + n] * f1);
        nv2[d * kPc + p] = tanh_f(cTA * e2T[d * kN + n] * f2);
    }
}

// ---------------------------------------------------------------------------
// fused a-GEMM + antisymmetrize: adjv[i][j] = relu(tanh(TA*(a_ij - a_ji)))
// a_ij = sum_d nv1[d,i]*nv2[d,j].  grid (6 jblk, 21 iblk, 32 b), block 64
__global__ __launch_bounds__(64) void k_adj(const float* __restrict__ nv1, const float* __restrict__ nv2,
                                            float* __restrict__ adjv) {
    int j = blockIdx.x * 64 + threadIdx.x;
    if (j >= kN) return;
    int i0 = blockIdx.y * 16;
    int b = blockIdx.z;
    const float* p1 = nv1 + b * kNP;
    const float* p2 = nv2 + b * kNP;
    float aij[16], aji[16];
#pragma unroll
    for (int q = 0; q < 16; ++q) { aij[q] = 0.f; aji[q] = 0.f; }
    for (int d = 0; d < kND; ++d) {
        const float* r1 = p1 + d * kPc;
        const float* r2 = p2 + d * kPc;
        float x1j = r1[j];
        float x2j = r2[j];
        float4 v1a = *(const float4*)(r1 + i0);
        float4 v1b = *(const float4*)(r1 + i0 + 4);
        float4 v1c = *(const float4*)(r1 + i0 + 8);
        float4 v1d = *(const float4*)(r1 + i0 + 12);
        float4 v2a = *(const float4*)(r2 + i0);
        float4 v2b = *(const float4*)(r2 + i0 + 4);
        float4 v2c = *(const float4*)(r2 + i0 + 8);
        float4 v2d = *(const float4*)(r2 + i0 + 12);
        const float* f1 = (const float*)&v1a;  // contiguous 16 via unions below
        float w1v[16] = {v1a.x,v1a.y,v1a.z,v1a.w, v1b.x,v1b.y,v1b.z,v1b.w,
                         v1c.x,v1c.y,v1c.z,v1c.w, v1d.x,v1d.y,v1d.z,v1d.w};
        float w2v[16] = {v2a.x,v2a.y,v2a.z,v2a.w, v2b.x,v2b.y,v2b.z,v2b.w,
                         v2c.x,v2c.y,v2c.z,v2c.w, v2d.x,v2d.y,v2d.z,v2d.w};
        (void)f1;
#pragma unroll
        for (int q = 0; q < 16; ++q) {
            aij[q] = fmaf(w1v[q], x2j, aij[q]);   // nv1[d,i]*nv2[d,j]
            aji[q] = fmaf(x1j, w2v[q], aji[q]);   // nv1[d,j]*nv2[d,i]
        }
    }
    size_t base = (size_t)b * kN * kN;
#pragma unroll
    for (int q = 0; q < 16; ++q) {
        int i = i0 + q;
        if (i < kN) {
            float tv = tanh_f(cTA * (aij[q] - aji[q]));
            adjv[base + (size_t)i * kN + j] = fmaxf(tv, 0.f);
        }
    }
}

// colsum: irs1[i] = 1/(1 + sum_j adjv[j][i]) — coalesced, 4 waves split j
__global__ __launch_bounds__(256) void k_colsum(const float* __restrict__ adjv, float* __restrict__ irs1) {
    __shared__ float red[4][64];
    int lane = threadIdx.x & 63, wv = threadIdx.x >> 6;
    int i = blockIdx.x * 64 + lane;
    int b = blockIdx.y;
    const float* base = adjv + (size_t)b * kN * kN;
    float cs = 0.f;
    if (i < kN)
        for (int j = wv; j < kN; j += 4) cs += base[(size_t)j * kN + i];
    red[wv][lane] = cs;
    __syncthreads();
    if (wv == 0 && i < kN) {
        float s = 1.f + red[0][lane] + red[1][lane] + red[2][lane] + red[3][lane];
        irs1[b * kN + i] = 1.f / s;
    }
}

// rowsum: one wave per (i,b), lanes over j (coalesced), shuffle-reduce
__global__ __launch_bounds__(64) void k_rowsum(const float* __restrict__ adjv, float* __restrict__ irs0) {
    int i = blockIdx.x, b = blockIdx.y, l = threadIdx.x;
    const float* row = adjv + (size_t)b * kN * kN + (size_t)i * kN;
    float s = 0.f;
    for (int j = l; j < kN; j += 64) s += row[j];
#pragma unroll
    for (int off = 32; off; off >>= 1) s += __shfl_down(s, off);
    if (l == 0) irs0[b * kN + i] = 1.f / (1.f + s);
}

// E0[v][w] = BW*(adjv[v][w]+I)*irs0[v] + GW*adj0[v][w]
// E1[v][w] = BW*(adjv[w][v]+I)*irs1[v] + GW*adj1[v][w]   (tiled-transpose in LDS)
__global__ __launch_bounds__(256) void k_buildE(const float* __restrict__ adjv,
                                                const float* __restrict__ adj0, const float* __restrict__ adj1,
                                                const float* __restrict__ irs0, const float* __restrict__ irs1,
                                                float* __restrict__ E0, float* __restrict__ E1) {
    __shared__ float tile[64][65];
    int lane = threadIdx.x & 63, wv = threadIdx.x >> 6;
    int w0 = blockIdx.x * 64, v0 = blockIdx.y * 64, b = blockIdx.z;
    const float* av = adjv + (size_t)b * kN * kN;
#pragma unroll 4
    for (int rr = 0; rr < 16; ++rr) {
        int r = wv * 16 + rr;
        int v = v0 + r, w = w0 + lane;
        tile[r][lane] = (v < kN && w < kN) ? av[(size_t)v * kN + w] : 0.f;
    }
    __syncthreads();
    size_t eb = (size_t)b * kN * kN;
#pragma unroll 2
    for (int rr = 0; rr < 16; ++rr) {
        int r = wv * 16 + rr;
        {
            int v = v0 + r, w = w0 + lane;
            if (v < kN && w < kN) {
                float iv = irs0[b * kN + v];
                float e = cBW * tile[r][lane] * iv + cGW * adj0[v * kN + w];
                if (v == w) e += cBW * iv;
                E0[eb + (size_t)v * kN + w] = e;
            }
        }
        {
            int v = w0 + r, w = v0 + lane;
            if (v < kN && w < kN) {
                float iv = irs1[b * kN + v];
                float e = cBW * tile[lane][r] * iv + cGW * adj1[v * kN + w];
                if (v == w) e += cBW * iv;
                E1[eb + (size_t)v * kN + w] = e;
            }
        }
    }
}

// ---------------------------------------------------------------------------
// z,r gates + temp = [x, r*H] into hoc buffers (rows 0..65) + AW*temp prefill
// of their hop slots (rows 66..197).  grid (164, 16), block 64
__global__ __launch_bounds__(64) void k_gates(const float* __restrict__ hz0, const float* __restrict__ hz1,
                                              const float* __restrict__ rnw, const float* __restrict__ rnb, int rb,
                                              const float* __restrict__ Hm, float* __restrict__ z,
                                              float* __restrict__ tc0, float* __restrict__ tc1) {
    int p = blockIdx.x * 64 + threadIdx.x;
    int h0 = blockIdx.y * 4;
    const float* wz0 = rnw + (rb + 0) * (kDIN * kHID) + h0;
    const float* wz1 = rnw + (rb + 1) * (kDIN * kHID) + h0;
    const float* wr0 = rnw + (rb + 2) * (kDIN * kHID) + h0;
    const float* wr1 = rnw + (rb + 3) * (kDIN * kHID) + h0;
    float az[4], ar[4];
#pragma unroll
    for (int i = 0; i < 4; ++i) { az[i] = 0.f; ar[i] = 0.f; }
#pragma unroll 2
    for (int k = 0; k < kDIN; ++k) {
        float u0 = hz0[k * kPc + p], u1 = hz1[k * kPc + p];
#pragma unroll
        for (int i = 0; i < 4; ++i) {
            az[i] = fmaf(u0, wz0[k * kHID + i], az[i]);
            az[i] = fmaf(u1, wz1[k * kHID + i], az[i]);
            ar[i] = fmaf(u0, wr0[k * kHID + i], ar[i]);
            ar[i] = fmaf(u1, wr1[k * kHID + i], ar[i]);
        }
    }
    int b = p / kNP, n = p - b * kNP;
    bool ok = (n < kN);
#pragma unroll
    for (int i = 0; i < 4; ++i) {
        float zz = sigm_f(az[i] + rnb[(rb + 0) * kHID + h0 + i] + rnb[(rb + 1) * kHID + h0 + i]);
        float rr = sigm_f(ar[i] + rnb[(rb + 2) * kHID + h0 + i] + rnb[(rb + 3) * kHID + h0 + i]);
        float tv = rr * Hm[(h0 + i) * kPc + p];
        float atv = cAW * tv;
        if (ok) {
            z[(h0 + i) * kPc + p] = zz;
            tc0[(2 + h0 + i) * kPc + p] = tv;   tc1[(2 + h0 + i) * kPc + p] = tv;
            tc0[(68 + h0 + i) * kPc + p] = atv; tc1[(68 + h0 + i) * kPc + p] = atv;
            tc0[(134 + h0 + i) * kPc + p] = atv; tc1[(134 + h0 + i) * kPc + p] = atv;
        }
    }
    if (blockIdx.y == 0 && ok) {
#pragma unroll
        for (int c = 0; c < 2; ++c) {
            float xv = hz0[c * kPc + p];
            float axv = cAW * xv;
            tc0[c * kPc + p] = xv;          tc1[c * kPc + p] = xv;
            tc0[(66 + c) * kPc + p] = axv;  tc1[(66 + c) * kPc + p] = axv;
            tc0[(132 + c) * kPc + p] = axv; tc1[(132 + c) * kPc + p] = axv;
        }
    }
}

// Cn + GRU update: H = z*H + (1-z)*tanh(...)
__global__ __launch_bounds__(64) void k_final(const float* __restrict__ hc0, const float* __restrict__ hc1,
                                              const float* __restrict__ rnw, const float* __restrict__ rnb, int rb,
                                              const float* __restrict__ z, float* __restrict__ Hm) {
    int p = blockIdx.x * 64 + threadIdx.x;
    int h0 = blockIdx.y * 8;
    const float* wc0 = rnw + (rb + 4) * (kDIN * kHID) + h0;
    const float* wc1 = rnw + (rb + 5) * (kDIN * kHID) + h0;
    float ac[8];
#pragma unroll
    for (int i = 0; i < 8; ++i) ac[i] = 0.f;
#pragma unroll 2
    for (int k = 0; k < kDIN; ++k) {
        float u0 = hc0[k * kPc + p], u1 = hc1[k * kPc + p];
#pragma unroll
        for (int i = 0; i < 8; ++i) {
            ac[i] = fmaf(u0, wc0[k * kHID + i], ac[i]);
            ac[i] = fmaf(u1, wc1[k * kHID + i], ac[i]);
        }
    }
    int b = p / kNP, n = p - b * kNP;
    if (n >= kN) return;
#pragma unroll
    for (int i = 0; i < 8; ++i) {
        float cn = tanh_f(ac[i] + rnb[(rb + 4) * kHID + h0 + i] + rnb[(rb + 5) * kHID + h0 + i]);
        float zz = z[(h0 + i) * kPc + p];
        float hv = Hm[(h0 + i) * kPc + p];
        Hm[(h0 + i) * kPc + p] = zz * hv + (1.f - zz) * cn;
    }
}

// decoder readout: out = H @ fc_w + fc_b ; prev = out
__global__ __launch_bounds__(64) void k_out(const float* __restrict__ Hm, const float* __restrict__ fw,
                                            const float* __restrict__ fb,
                                            float* __restrict__ out, float* __restrict__ prev, int t) {
    int p = blockIdx.x * 64 + threadIdx.x;
    int b = p / kNP, n = p - b * kNP;
    if (n >= kN) return;
    float acc = fb[0];
#pragma unroll
    for (int h = 0; h < kHID; ++h) acc = fmaf(Hm[h * kPc + p], fw[h], acc);
    out[(b * 12 + t) * kN + n] = acc;
    prev[p] = acc;
}

// ---------------------------------------------------------------------------
extern "C" void kernel_launch(void* const* d_in, const int* in_sizes, int n_in,
                              void* d_out, int out_size, void* d_ws, size_t ws_size,
                              hipStream_t stream) {
    const float* hist = (const float*)d_in[0];
    const float* fut  = (const float*)d_in[1];
    const float* adj0 = (const float*)d_in[2];
    const float* adj1 = (const float*)d_in[3];
    const float* emb1 = (const float*)d_in[4];
    const float* emb2 = (const float*)d_in[5];
    const float* hw1  = (const float*)d_in[6];
    const float* hb1  = (const float*)d_in[7];
    const float* hw2  = (const float*)d_in[8];
    const float* hb2  = (const float*)d_in[9];
    const float* hw3  = (const float*)d_in[10];
    const float* hb3  = (const float*)d_in[11];
    const float* rnw  = (const float*)d_in[12];
    const float* rnb  = (const float*)d_in[13];
    const float* fcw  = (const float*)d_in[14];
    const float* fcb  = (const float*)d_in[15];
    float* out = (float*)d_out;
    float* ws  = (float*)d_ws;

    size_t off = 0;
    float* Hm   = ws + off; off += 64 * kPc;
    float* hoh0 = ws + off; off += kDIN * kPc;   // hyper chain A0, reused as ho_c0
    float* hoh1 = ws + off; off += kDIN * kPc;   // hyper chain A1, reused as ho_c1
    float* hoz0 = ws + off; off += kDIN * kPc;   // rnn chain adp/adj0
    float* hoz1 = ws + off; off += kDIN * kPc;   // rnn chain adpT/adj1
    float* nv1  = ws + off; off += kND * kPc;
    float* nv2  = ws + off; off += kND * kPc;
    float* s1   = ws + off; off += 64 * kPc;
    float* zbuf = ws + off; off += 64 * kPc;
    float* prev = ws + off; off += kPc;
    float* adjv = ws + off; off += (size_t)kB * kN * kN;
    float* E0   = ws + off; off += (size_t)kB * kN * kN;
    float* E1   = ws + off; off += (size_t)kB * kN * kN;
    float* irs0 = ws + off; off += kB * kN;
    float* irs1 = ws + off; off += kB * kN;
    float* e1T  = ws + off; off += kND * kN;
    float* e2T  = ws + off; off += kND * kN;
    float* hoc0 = hoh0;
    float* hoc1 = hoh1;

    const int NN2 = kN * kN;

    {
        int tot = 64 * kPc + kPc + 2 * kND * kN;
        k_init<<<dim3((tot + 255) / 256), dim3(256), 0, stream>>>(emb1, emb2, Hm, prev, e1T, e2T);
    }

    for (int step = 0; step < 24; ++step) {
        int dec = step >= 12;
        int t = dec ? step - 12 : step;
        int hy0 = dec ? 4 : 0;
        int rb = dec ? 6 : 0;

        k_build<<<dim3((66 * kPc) / 256), dim3(256), 0, stream>>>(
            hist, fut, Hm, prev, t, dec, hoh0, hoh1, hoz0, hoz1);

        // hyper diffusion (static adjacencies)
        k_hop<<<dim3(6, 6, 128), dim3(64), 0, stream>>>(
            adj0, adj1, 0, hoh0, hoh1, hoh0 + 66 * kPc, hoh1 + 66 * kPc, cGW);
        k_hop<<<dim3(6, 6, 128), dim3(64), 0, stream>>>(
            adj0, adj1, 0, hoh0 + 66 * kPc, hoh1 + 66 * kPc, hoh0 + 132 * kPc, hoh1 + 132 * kPc, cGW);

        k_mlp1<<<dim3(kPc / 64, 4), dim3(64), 0, stream>>>(hoh0, hoh1, hw1, hb1, s1, hy0);
        k_mlp2<<<dim3(kPc / 64), dim3(64), 0, stream>>>(s1, hw2, hb2, hw3, hb3, e1T, e2T, nv1, nv2, hy0);

        k_adj<<<dim3(6, 21, kB), dim3(64), 0, stream>>>(nv1, nv2, adjv);
        k_colsum<<<dim3(6, kB), dim3(256), 0, stream>>>(adjv, irs1);
        k_rowsum<<<dim3(kN, kB), dim3(64), 0, stream>>>(adjv, irs0);
        k_buildE<<<dim3(6, 6, kB), dim3(256), 0, stream>>>(adjv, adj0, adj1, irs0, irs1, E0, E1);

        // rnn diffusion on hi
        k_hop<<<dim3(6, 6, 128), dim3(64), 0, stream>>>(
            E0, E1, NN2, hoz0, hoz1, hoz0 + 66 * kPc, hoz1 + 66 * kPc, 1.f);
        k_hop<<<dim3(6, 6, 128), dim3(64), 0, stream>>>(
            E0, E1, NN2, hoz0 + 66 * kPc, hoz1 + 66 * kPc, hoz0 + 132 * kPc, hoz1 + 132 * kPc, 1.f);

        k_gates<<<dim3(kPc / 64, 16), dim3(64), 0, stream>>>(hoz0, hoz1, rnw, rnb, rb, Hm, zbuf, hoc0, hoc1);

        // rnn diffusion on temp
        k_hop<<<dim3(6, 6, 128), dim3(64), 0, stream>>>(
            E0, E1, NN2, hoc0, hoc1, hoc0 + 66 * kPc, hoc1 + 66 * kPc, 1.f);
        k_hop<<<dim3(6, 6, 128), dim3(64), 0, stream>>>(
            E0, E1, NN2, hoc0 + 66 * kPc, hoc1 + 66 * kPc, hoc0 + 132 * kPc, hoc1 + 132 * kPc, 1.f);

        k_final<<<dim3(kPc / 64, 8), dim3(64), 0, stream>>>(hoc0, hoc1, rnw, rnb, rb, zbuf, Hm);

        if (dec)
            k_out<<<dim3(kPc / 64), dim3(64), 0, stream>>>(Hm, fcw, fcb, out, prev, t);
    }
    (void)in_sizes; (void)n_in; (void)out_size; (void)ws_size;
}